// Round 5
// baseline (147.070 us; speedup 1.0000x reference)
//
#include <hip/hip_runtime.h>

typedef __attribute__((ext_vector_type(8)))  short short8;
typedef __attribute__((ext_vector_type(16))) float f32x16;

// ws layout (bytes)
#define OFF_S1 0          // 8 panels x 16384  ([64c][128k], cols = v(32)+g(32), k-half e)
#define OFF_S2 131072     // 4 panels x 16384  ([64c][128k])
#define OFF_S3 196608     // 4 panels x 8192   ([32c][128k])
#define OFF_S4 229376     // 2 panels x 8192   ([32c][128k])
#define OFF_B  245760     // 704 f32: B1[256] B2[256] B3[128] B4[64]

#define L2E 1.44269504088896340736f

__device__ __forceinline__ unsigned short f2bf(float f){
  unsigned u = __builtin_bit_cast(unsigned, f);
  return (unsigned short)((u + 0x7fffu + ((u >> 16) & 1u)) >> 16);  // RNE
}
__device__ __forceinline__ float bf2f(short s){
  return __builtin_bit_cast(float, ((unsigned)(unsigned short)s) << 16);
}
__device__ __forceinline__ unsigned pk2(float lo, float hi){
  unsigned r;
  asm("v_cvt_pk_bf16_f32 %0, %1, %2" : "=v"(r) : "v"(lo), "v"(hi));
  return r;
}
__device__ __forceinline__ float fexp2n(float x){   // exp2(-x)
  float r; asm("v_exp_f32 %0, -%1" : "=v"(r) : "v"(x)); return r;
}
__device__ __forceinline__ float frcp(float x){
  float r; asm("v_rcp_f32 %0, %1" : "=v"(r) : "v"(x)); return r;
}

// ---------------- prep: fold BN (+log2e on gate half), build swizzled A-panels ----------------
// panel byte for col cc, k kl: cc*256 + ((kl*2) ^ ((cc&15)<<4))
__global__ void tabnet_prep(
    const float* __restrict__ w1, const float* __restrict__ b1, const float* __restrict__ g1, const float* __restrict__ be1,
    const float* __restrict__ w2, const float* __restrict__ b2, const float* __restrict__ g2, const float* __restrict__ be2,
    const float* __restrict__ aw, const float* __restrict__ ab, const float* __restrict__ ag, const float* __restrict__ abe,
    const float* __restrict__ ow, const float* __restrict__ ob, unsigned char* __restrict__ ws)
{
  const float inv = 1.0f / sqrtf(1.0f + 1e-3f);
  int tid = blockIdx.x * blockDim.x + threadIdx.x;
  int np  = gridDim.x * blockDim.x;

  // W1 [256k][256c] -> s1 panels (pair m, khalf e); gate cols (c>=128) pre-scaled by log2e
  for (int i = tid; i < 256*256; i += np){
    int k = i >> 8, c = i & 255;
    int m, cc; float sc;
    if (c < 128){ m = c >> 5; cc = c & 31; sc = 1.f; }
    else        { m = (c-128) >> 5; cc = 32 + ((c-128) & 31); sc = L2E; }
    int e = k >> 7, kl = k & 127;
    size_t byte = OFF_S1 + (size_t)(m*2+e)*16384 + cc*256 + (((kl<<1)) ^ ((cc&15)<<4));
    *(unsigned short*)(ws + byte) = f2bf(w1[k*256+c] * (g1[c]*inv) * sc);
  }
  // W2 [128k][256c] -> s2 panels
  for (int i = tid; i < 128*256; i += np){
    int k = i >> 8, c = i & 255;
    int m, cc; float sc;
    if (c < 128){ m = c >> 5; cc = c & 31; sc = 1.f; }
    else        { m = (c-128) >> 5; cc = 32 + ((c-128) & 31); sc = L2E; }
    size_t byte = OFF_S2 + (size_t)m*16384 + cc*256 + (((k<<1)) ^ ((cc&15)<<4));
    *(unsigned short*)(ws + byte) = f2bf(w2[k*256+c] * (g2[c]*inv) * sc);
  }
  // att_w[4] [128k][128c] -> s3 panels
  for (int i = tid; i < 128*128; i += np){
    int k = i >> 7, c = i & 127;
    int m = c >> 5, cc = c & 31;
    size_t byte = OFF_S3 + (size_t)m*8192 + cc*256 + (((k<<1)) ^ ((cc&15)<<4));
    *(unsigned short*)(ws + byte) = f2bf(aw[4*128*128 + k*128 + c] * (ag[4*128+c]*inv));
  }
  // out_w [128k][64c] -> s4 panels
  for (int i = tid; i < 128*64; i += np){
    int k = i >> 6, c = i & 63;
    int m = c >> 5, cc = c & 31;
    size_t byte = OFF_S4 + (size_t)m*8192 + cc*256 + (((k<<1)) ^ ((cc&15)<<4));
    *(unsigned short*)(ws + byte) = f2bf(ow[k*64 + c]);
  }
  float* B = (float*)(ws + OFF_B);
  for (int i = tid; i < 256; i += np){
    float sc = (i < 128) ? 1.f : L2E;
    B[i]     = (b1[i]*(g1[i]*inv) + be1[i]) * sc;
    B[256+i] = (b2[i]*(g2[i]*inv) + be2[i]) * sc;
  }
  for (int i = tid; i < 128; i += np){ B[512+i] = ab[4*128+i]*(ag[4*128+i]*inv) + abe[4*128+i]; }
  for (int i = tid; i < 64;  i += np){ B[640+i] = ob[i]; }
}

// ---------------- main ----------------
#define FENCE() __builtin_amdgcn_sched_barrier(0)
template<int N> __device__ __forceinline__ void waitv(){
  asm volatile("s_waitcnt vmcnt(%0)" :: "i"(N) : "memory");
}
__device__ __forceinline__ void barx(){ FENCE(); __builtin_amdgcn_s_barrier(); FENCE(); }

__device__ __forceinline__ void gl_lds16(const void* g, void* l){
  __builtin_amdgcn_global_load_lds(
      (const __attribute__((address_space(1))) unsigned int*)g,
      (__attribute__((address_space(3))) unsigned int*)l, 16, 0, 0);
}

// stage a panel: R rounds of 4KB; wave w covers [w*1024, +1024) of each round
template<int R>
__device__ __forceinline__ void stage_panel(const unsigned char* src, unsigned char* lds, int w, int l){
  #pragma unroll
  for (int j = 0; j < R; ++j)
    gl_lds16(src + j*4096 + w*1024 + l*16, lds + j*4096 + w*1024);
}

__device__ __forceinline__ f32x16 zero16(){
  f32x16 z;
  #pragma unroll
  for (int i = 0; i < 16; ++i) z[i] = 0.f;
  return z;
}

// A-frag read, 4-bit XOR swizzle: 16B slot = ((kb<<1)|lh) ^ (cc&15)
__device__ __forceinline__ short8 afrag(const unsigned char* buf, int cc, int kb, int lh){
  int off = cc*256 + ((((kb<<1) | lh) ^ (cc & 15)) << 4);
  return *(const short8*)(buf + off);
}

__device__ __forceinline__ unsigned sx32(unsigned v){ return (unsigned)__shfl_xor((int)v, 32, 64); }
__device__ __forceinline__ float    sx32f(float v){ return __shfl_xor(v, 32, 64); }

// build B-frags for kb = 2m, 2m+1 from 8 packed words (W[q] = bf16x2 of D-regs 2q,2q+1)
// R3-proven shuffle+select form.
__device__ __forceinline__ void frags_from_words(const unsigned* W, int lh, short8* f0, short8* f1){
  #pragma unroll
  for (int kbl = 0; kbl < 2; ++kbl){
    const int g0 = kbl*2;
    unsigned own0 = lh ? W[2*(g0+1)]   : W[2*g0];
    unsigned own1 = lh ? W[2*(g0+1)+1] : W[2*g0+1];
    unsigned snd0 = lh ? W[2*g0]       : W[2*(g0+1)];
    unsigned snd1 = lh ? W[2*g0+1]     : W[2*(g0+1)+1];
    unsigned r0 = sx32(snd0), r1 = sx32(snd1);
    uint4 fw;
    fw.x = lh ? r0 : own0;   // j0,j1 (from lower half)
    fw.y = lh ? r1 : own1;   // j2,j3
    fw.z = lh ? own0 : r0;   // j4,j5 (from upper half)
    fw.w = lh ? own1 : r1;   // j6,j7
    short8 f = __builtin_bit_cast(short8, fw);
    if (kbl == 0) *f0 = f; else *f1 = f;
  }
}

__global__ void __launch_bounds__(256, 4) tabnet_main(
    const float* __restrict__ X, const unsigned char* __restrict__ ws, float* __restrict__ out)
{
  __shared__ __align__(16) unsigned char buf[2][16384];
  __shared__ __align__(16) float blds[704];

  const int tid = threadIdx.x;
  const int w   = tid >> 6;
  const int l   = tid & 63;
  const int lh  = l >> 5;      // lane half
  const int cc  = l & 31;      // col-lane / row-lane
  const long rowbase = (long)blockIdx.x * 128 + w * 32;

  // ---- prologue staging: P0, P1, biases ----
  stage_panel<4>(ws + OFF_S1,         buf[0], w, l);
  stage_panel<4>(ws + OFF_S1 + 16384, buf[1], w, l);
  if (w == 0){
    #pragma unroll
    for (int j = 0; j < 3; ++j)
      if (j*1024 + l*16 < 2816)
        gl_lds16(ws + OFF_B + j*1024 + l*16, (unsigned char*)blds + j*1024);
  }

  // ---- X load (32 rows x 256 k, one burst) + cvt to bf16 B-frags ----
  const float* xp = X + (rowbase + cc) * 256 + lh * 8;
  float4 xfa[16], xfb[16];
  #pragma unroll
  for (int K = 0; K < 16; ++K){
    xfa[K] = *(const float4*)(xp + K*16);
    xfb[K] = *(const float4*)(xp + K*16 + 4);
  }
  short8 xb[16];
  #pragma unroll
  for (int K = 0; K < 16; ++K){
    uint4 u;
    u.x = pk2(xfa[K].x, xfa[K].y); u.y = pk2(xfa[K].z, xfa[K].w);
    u.z = pk2(xfb[K].x, xfb[K].y); u.w = pk2(xfb[K].z, xfb[K].w);
    xb[K] = __builtin_bit_cast(short8, u);
  }
  barx();   // all waves: P0,P1,bias staged (vmcnt drained by cvt chain)

  // ================= stage 1: X @ W1 -> GLU -> T1-frags =================
  short8 t1b[8];
  #pragma unroll
  for (int m = 0; m < 4; ++m){
    f32x16 accv = zero16(), accg = zero16();
    #pragma unroll
    for (int e = 0; e < 2; ++e){
      const int p = m*2 + e;
      waitv<4>(); barx();
      const unsigned char* bp = buf[p & 1];
      #pragma unroll
      for (int kb = 0; kb < 8; ++kb){
        short8 av = afrag(bp, cc,      kb, lh);
        short8 ag = afrag(bp, cc + 32, kb, lh);
        const int K = e*8 + kb;
        accv = __builtin_amdgcn_mfma_f32_32x32x16_bf16(av, xb[K], accv, 0, 0, 0);
        accg = __builtin_amdgcn_mfma_f32_32x32x16_bf16(ag, xb[K], accg, 0, 0, 0);
      }
      barx();
      // stage P_{p+2}
      if (p+2 <= 7)       stage_panel<4>(ws + OFF_S1 + (p+2)*16384, buf[p & 1], w, l);
      else                stage_panel<4>(ws + OFF_S2 + (p-6)*16384, buf[p & 1], w, l);
    }
    // GLU epilogue -> packed words -> exchange -> frags kb 2m,2m+1
    unsigned W[8];
    #pragma unroll
    for (int q = 0; q < 4; ++q){
      float4 bv = *(const float4*)&blds[      m*32 + 8*q + 4*lh];
      float4 bg = *(const float4*)&blds[128 + m*32 + 8*q + 4*lh];
      float t0 = (accv[4*q+0] + bv.x) * frcp(1.f + fexp2n(accg[4*q+0] + bg.x));
      float t1 = (accv[4*q+1] + bv.y) * frcp(1.f + fexp2n(accg[4*q+1] + bg.y));
      float t2 = (accv[4*q+2] + bv.z) * frcp(1.f + fexp2n(accg[4*q+2] + bg.z));
      float t3 = (accv[4*q+3] + bv.w) * frcp(1.f + fexp2n(accg[4*q+3] + bg.w));
      W[2*q]   = pk2(t0, t1);
      W[2*q+1] = pk2(t2, t3);
    }
    frags_from_words(W, lh, &t1b[2*m], &t1b[2*m+1]);
  }

  // ================= stage 2: T1 @ W2 -> GLU -> T-frags =================
  short8 tb[8];
  #pragma unroll
  for (int m = 0; m < 4; ++m){
    const int p = 8 + m;
    f32x16 accv = zero16(), accg = zero16();
    if (p == 11) waitv<2>(); else waitv<4>();
    barx();
    const unsigned char* bp = buf[p & 1];
    #pragma unroll
    for (int kb = 0; kb < 8; ++kb){
      short8 av = afrag(bp, cc,      kb, lh);
      short8 ag = afrag(bp, cc + 32, kb, lh);
      accv = __builtin_amdgcn_mfma_f32_32x32x16_bf16(av, t1b[kb], accv, 0, 0, 0);
      accg = __builtin_amdgcn_mfma_f32_32x32x16_bf16(ag, t1b[kb], accg, 0, 0, 0);
    }
    barx();
    if (p+2 <= 11) stage_panel<4>(ws + OFF_S2 + (p-6)*16384, buf[p & 1], w, l);
    else           stage_panel<2>(ws + OFF_S3 + (p-10)*8192, buf[p & 1], w, l);
    unsigned W[8];
    #pragma unroll
    for (int q = 0; q < 4; ++q){
      float4 bv = *(const float4*)&blds[256 +       m*32 + 8*q + 4*lh];
      float4 bg = *(const float4*)&blds[256 + 128 + m*32 + 8*q + 4*lh];
      float t0 = (accv[4*q+0] + bv.x) * frcp(1.f + fexp2n(accg[4*q+0] + bg.x));
      float t1 = (accv[4*q+1] + bv.y) * frcp(1.f + fexp2n(accg[4*q+1] + bg.y));
      float t2 = (accv[4*q+2] + bv.z) * frcp(1.f + fexp2n(accg[4*q+2] + bg.z));
      float t3 = (accv[4*q+3] + bv.w) * frcp(1.f + fexp2n(accg[4*q+3] + bg.w));
      W[2*q]   = pk2(t0, t1);
      W[2*q+1] = pk2(t2, t3);
    }
    frags_from_words(W, lh, &tb[2*m], &tb[2*m+1]);
  }

  // ================= stage 3: T @ att_w4 -> z =================
  f32x16 zc[4];
  #pragma unroll
  for (int m = 0; m < 4; ++m){
    const int p = 12 + m;
    f32x16 acc = zero16();
    waitv<2>(); barx();
    const unsigned char* bp = buf[p & 1];
    #pragma unroll
    for (int kb = 0; kb < 8; ++kb){
      short8 a = afrag(bp, cc, kb, lh);
      acc = __builtin_amdgcn_mfma_f32_32x32x16_bf16(a, tb[kb], acc, 0, 0, 0);
    }
    barx();
    if (p+2 <= 15) stage_panel<2>(ws + OFF_S3 + (p-10)*8192, buf[p & 1], w, l);
    else           stage_panel<2>(ws + OFF_S4 + (p-14)*8192, buf[p & 1], w, l);
    #pragma unroll
    for (int q = 0; q < 4; ++q){
      float4 b3 = *(const float4*)&blds[512 + m*32 + 8*q + 4*lh];
      zc[m][4*q+0] = acc[4*q+0] + b3.x;
      zc[m][4*q+1] = acc[4*q+1] + b3.y;
      zc[m][4*q+2] = acc[4*q+2] + b3.z;
      zc[m][4*q+3] = acc[4*q+3] + b3.w;
    }
  }

  // ---- sparsemax per row (row = cc, halves on lanes l and l^32) ----
  float tau, cprev;
  {
    float s = 0.f;
    #pragma unroll
    for (int m = 0; m < 4; ++m)
      #pragma unroll
      for (int i = 0; i < 16; ++i) s += zc[m][i];
    s += sx32f(s);
    tau = (s - 1.f) * (1.f/128.f);
    cprev = 128.f;
  }
  for (int it = 0; it < 32; ++it){
    float s2 = 0.f, c2 = 0.f;
    #pragma unroll
    for (int m = 0; m < 4; ++m)
      #pragma unroll
      for (int i = 0; i < 16; ++i){
        float z = zc[m][i];
        if (z > tau){ s2 += z; c2 += 1.f; }
      }
    s2 += sx32f(s2); c2 += sx32f(c2);
    tau = (s2 - 1.f) / c2;
    int ch = (c2 != cprev);
    cprev = c2;
    if (!__any(ch)) break;
  }

  // ---- P-frags: exchange z to B-layout (f32), multiply with T, pack ----
  short8 pb[8];
  #pragma unroll
  for (int kb = 0; kb < 8; ++kb){
    const int chn = kb >> 1;
    const int ga = (kb & 1) * 2;
    float o[4], sn[4], rv[4];
    #pragma unroll
    for (int i = 0; i < 4; ++i){
      o[i]  = lh ? zc[chn][4*(ga+1) + i] : zc[chn][4*ga + i];
      sn[i] = lh ? zc[chn][4*ga + i]     : zc[chn][4*(ga+1) + i];
    }
    #pragma unroll
    for (int i = 0; i < 4; ++i) rv[i] = sx32f(sn[i]);
    float zB[8];
    #pragma unroll
    for (int i = 0; i < 4; ++i){
      zB[i]   = lh ? rv[i] : o[i];
      zB[4+i] = lh ? o[i]  : rv[i];
    }
    float P[8];
    #pragma unroll
    for (int j = 0; j < 8; ++j){
      float mk = zB[j] - tau;
      mk = mk > 0.f ? mk : 0.f;
      P[j] = bf2f(tb[kb][j]) * mk;
    }
    uint4 u;
    u.x = pk2(P[0], P[1]); u.y = pk2(P[2], P[3]);
    u.z = pk2(P[4], P[5]); u.w = pk2(P[6], P[7]);
    pb[kb] = __builtin_bit_cast(short8, u);
  }

  // ================= stage 4: P @ out_w + b -> out =================
  #pragma unroll
  for (int m = 0; m < 2; ++m){
    const int p = 16 + m;
    f32x16 acc = zero16();
    if (p == 17) waitv<0>(); else waitv<2>();
    barx();
    const unsigned char* bp = buf[p & 1];
    #pragma unroll
    for (int kb = 0; kb < 8; ++kb){
      short8 a = afrag(bp, cc, kb, lh);
      acc = __builtin_amdgcn_mfma_f32_32x32x16_bf16(a, pb[kb], acc, 0, 0, 0);
    }
    #pragma unroll
    for (int q = 0; q < 4; ++q){
      float4 b4 = *(const float4*)&blds[640 + m*32 + 8*q + 4*lh];
      float4 o4;
      o4.x = acc[4*q+0] + b4.x;
      o4.y = acc[4*q+1] + b4.y;
      o4.z = acc[4*q+2] + b4.z;
      o4.w = acc[4*q+3] + b4.w;
      *(float4*)&out[(rowbase + cc)*64 + m*32 + 8*q + 4*lh] = o4;
    }
  }
}

extern "C" void kernel_launch(void* const* d_in, const int* in_sizes, int n_in,
                              void* d_out, int out_size, void* d_ws, size_t ws_size,
                              hipStream_t stream)
{
  const float* feat = (const float*)d_in[0];
  const float* w1  = (const float*)d_in[1];
  const float* b1  = (const float*)d_in[2];
  const float* g1  = (const float*)d_in[3];
  const float* be1 = (const float*)d_in[4];
  const float* w2  = (const float*)d_in[5];
  const float* b2  = (const float*)d_in[6];
  const float* g2  = (const float*)d_in[7];
  const float* be2 = (const float*)d_in[8];
  const float* aw  = (const float*)d_in[9];
  const float* ab  = (const float*)d_in[10];
  const float* ag  = (const float*)d_in[11];
  const float* abe = (const float*)d_in[12];
  const float* ow  = (const float*)d_in[13];
  const float* ob  = (const float*)d_in[14];
  unsigned char* ws = (unsigned char*)d_ws;

  tabnet_prep<<<128, 256, 0, stream>>>(w1,b1,g1,be1, w2,b2,g2,be2, aw,ab,ag,abe, ow,ob, ws);
  tabnet_main<<<2048, 256, 0, stream>>>(feat, ws, (float*)d_out);
}

// Round 6
// 125.953 us; speedup vs baseline: 1.1677x; 1.1677x over previous
//
#include <hip/hip_runtime.h>

typedef __attribute__((ext_vector_type(8)))  short short8;
typedef __attribute__((ext_vector_type(16))) float f32x16;

// ws layout (bytes)
#define OFF_S1 0          // 8 panels x 16384  ([64c][128k], cols = v(32)+g(32), k-half e)
#define OFF_S2 131072     // 4 panels x 16384  ([64c][128k])
#define OFF_S3 196608     // 4 panels x 8192   ([32c][128k])
#define OFF_S4 229376     // 2 panels x 8192   ([32c][128k])
#define OFF_B  245760     // 704 f32: B1[256] B2[256] B3[128] B4[64]

#define L2E 1.44269504088896340736f

__device__ __forceinline__ unsigned short f2bf(float f){
  unsigned u = __builtin_bit_cast(unsigned, f);
  return (unsigned short)((u + 0x7fffu + ((u >> 16) & 1u)) >> 16);  // RNE
}
__device__ __forceinline__ float bf2f(short s){
  return __builtin_bit_cast(float, ((unsigned)(unsigned short)s) << 16);
}
__device__ __forceinline__ unsigned pk2(float lo, float hi){
  unsigned r;
  asm("v_cvt_pk_bf16_f32 %0, %1, %2" : "=v"(r) : "v"(lo), "v"(hi));
  return r;
}
__device__ __forceinline__ float fexp2n(float x){   // exp2(-x)
  float r; asm("v_exp_f32 %0, -%1" : "=v"(r) : "v"(x)); return r;
}
__device__ __forceinline__ float frcp(float x){
  float r; asm("v_rcp_f32 %0, %1" : "=v"(r) : "v"(x)); return r;
}

// ---------------- prep: fold BN (+log2e on gate half), build swizzled A-panels ----------------
// panel byte for col cc, k kl: cc*256 + ((kl*2) ^ ((cc&15)<<4))
__global__ void tabnet_prep(
    const float* __restrict__ w1, const float* __restrict__ b1, const float* __restrict__ g1, const float* __restrict__ be1,
    const float* __restrict__ w2, const float* __restrict__ b2, const float* __restrict__ g2, const float* __restrict__ be2,
    const float* __restrict__ aw, const float* __restrict__ ab, const float* __restrict__ ag, const float* __restrict__ abe,
    const float* __restrict__ ow, const float* __restrict__ ob, unsigned char* __restrict__ ws)
{
  const float inv = 1.0f / sqrtf(1.0f + 1e-3f);
  int tid = blockIdx.x * blockDim.x + threadIdx.x;
  int np  = gridDim.x * blockDim.x;

  // W1 [256k][256c] -> s1 panels (pair m, khalf e); gate cols (c>=128) pre-scaled by log2e
  for (int i = tid; i < 256*256; i += np){
    int k = i >> 8, c = i & 255;
    int m, cc; float sc;
    if (c < 128){ m = c >> 5; cc = c & 31; sc = 1.f; }
    else        { m = (c-128) >> 5; cc = 32 + ((c-128) & 31); sc = L2E; }
    int e = k >> 7, kl = k & 127;
    size_t byte = OFF_S1 + (size_t)(m*2+e)*16384 + cc*256 + (((kl<<1)) ^ ((cc&15)<<4));
    *(unsigned short*)(ws + byte) = f2bf(w1[k*256+c] * (g1[c]*inv) * sc);
  }
  // W2 [128k][256c] -> s2 panels
  for (int i = tid; i < 128*256; i += np){
    int k = i >> 8, c = i & 255;
    int m, cc; float sc;
    if (c < 128){ m = c >> 5; cc = c & 31; sc = 1.f; }
    else        { m = (c-128) >> 5; cc = 32 + ((c-128) & 31); sc = L2E; }
    size_t byte = OFF_S2 + (size_t)m*16384 + cc*256 + (((k<<1)) ^ ((cc&15)<<4));
    *(unsigned short*)(ws + byte) = f2bf(w2[k*256+c] * (g2[c]*inv) * sc);
  }
  // att_w[4] [128k][128c] -> s3 panels
  for (int i = tid; i < 128*128; i += np){
    int k = i >> 7, c = i & 127;
    int m = c >> 5, cc = c & 31;
    size_t byte = OFF_S3 + (size_t)m*8192 + cc*256 + (((k<<1)) ^ ((cc&15)<<4));
    *(unsigned short*)(ws + byte) = f2bf(aw[4*128*128 + k*128 + c] * (ag[4*128+c]*inv));
  }
  // out_w [128k][64c] -> s4 panels
  for (int i = tid; i < 128*64; i += np){
    int k = i >> 6, c = i & 63;
    int m = c >> 5, cc = c & 31;
    size_t byte = OFF_S4 + (size_t)m*8192 + cc*256 + (((k<<1)) ^ ((cc&15)<<4));
    *(unsigned short*)(ws + byte) = f2bf(ow[k*64 + c]);
  }
  float* B = (float*)(ws + OFF_B);
  for (int i = tid; i < 256; i += np){
    float sc = (i < 128) ? 1.f : L2E;
    B[i]     = (b1[i]*(g1[i]*inv) + be1[i]) * sc;
    B[256+i] = (b2[i]*(g2[i]*inv) + be2[i]) * sc;
  }
  for (int i = tid; i < 128; i += np){ B[512+i] = ab[4*128+i]*(ag[4*128+i]*inv) + abe[4*128+i]; }
  for (int i = tid; i < 64;  i += np){ B[640+i] = ob[i]; }
}

// ---------------- main ----------------
#define FENCE() __builtin_amdgcn_sched_barrier(0)
template<int N> __device__ __forceinline__ void waitv(){
  asm volatile("s_waitcnt vmcnt(%0)" :: "i"(N) : "memory");
}
__device__ __forceinline__ void barx(){ FENCE(); __builtin_amdgcn_s_barrier(); FENCE(); }

__device__ __forceinline__ void gl_lds16(const void* g, void* l){
  __builtin_amdgcn_global_load_lds(
      (const __attribute__((address_space(1))) unsigned int*)g,
      (__attribute__((address_space(3))) unsigned int*)l, 16, 0, 0);
}

// stage a panel: R rounds of 4KB; wave w covers [w*1024, +1024) of each round
template<int R>
__device__ __forceinline__ void stage_panel(const unsigned char* src, unsigned char* lds, int w, int l){
  #pragma unroll
  for (int j = 0; j < R; ++j)
    gl_lds16(src + j*4096 + w*1024 + l*16, lds + j*4096 + w*1024);
}

__device__ __forceinline__ f32x16 zero16(){
  f32x16 z;
  #pragma unroll
  for (int i = 0; i < 16; ++i) z[i] = 0.f;
  return z;
}

// A-frag read, 4-bit XOR swizzle: 16B slot = ((kb<<1)|lh) ^ (cc&15)
__device__ __forceinline__ short8 afrag(const unsigned char* buf, int cc, int kb, int lh){
  int off = cc*256 + ((((kb<<1) | lh) ^ (cc & 15)) << 4);
  return *(const short8*)(buf + off);
}

__device__ __forceinline__ unsigned sx32(unsigned v){ return (unsigned)__shfl_xor((int)v, 32, 64); }
__device__ __forceinline__ float    sx32f(float v){ return __shfl_xor(v, 32, 64); }

// build B-frags for kb = 2m, 2m+1 from 8 packed words (W[q] = bf16x2 of D-regs 2q,2q+1)
// R3-proven shuffle+select form.
__device__ __forceinline__ void frags_from_words(const unsigned* W, int lh, short8* f0, short8* f1){
  #pragma unroll
  for (int kbl = 0; kbl < 2; ++kbl){
    const int g0 = kbl*2;
    unsigned own0 = lh ? W[2*(g0+1)]   : W[2*g0];
    unsigned own1 = lh ? W[2*(g0+1)+1] : W[2*g0+1];
    unsigned snd0 = lh ? W[2*g0]       : W[2*(g0+1)];
    unsigned snd1 = lh ? W[2*g0+1]     : W[2*(g0+1)+1];
    unsigned r0 = sx32(snd0), r1 = sx32(snd1);
    uint4 fw;
    fw.x = lh ? r0 : own0;   // j0,j1 (from lower half)
    fw.y = lh ? r1 : own1;   // j2,j3
    fw.z = lh ? own0 : r0;   // j4,j5 (from upper half)
    fw.w = lh ? own1 : r1;   // j6,j7
    short8 f = __builtin_bit_cast(short8, fw);
    if (kbl == 0) *f0 = f; else *f1 = f;
  }
}

__global__ void __launch_bounds__(256, 3) tabnet_main(
    const float* __restrict__ X, const unsigned char* __restrict__ ws, float* __restrict__ out)
{
  __shared__ __align__(16) unsigned char buf[3][16384];   // 3-buffer rotation
  __shared__ __align__(16) float blds[704];

  const int tid = threadIdx.x;
  const int w   = tid >> 6;
  const int l   = tid & 63;
  const int lh  = l >> 5;      // lane half
  const int cc  = l & 31;      // col-lane / row-lane
  const long rowbase = (long)blockIdx.x * 128 + w * 32;

  // ---- prologue staging: P0, P1, biases ----
  stage_panel<4>(ws + OFF_S1,         buf[0], w, l);
  stage_panel<4>(ws + OFF_S1 + 16384, buf[1], w, l);
  if (w == 0){
    #pragma unroll
    for (int j = 0; j < 3; ++j)
      if (j*1024 + l*16 < 2816)
        gl_lds16(ws + OFF_B + j*1024 + l*16, (unsigned char*)blds + j*1024);
  }

  // ---- X load (32 rows x 256 k, one burst) + cvt to bf16 B-frags ----
  const float* xp = X + (rowbase + cc) * 256 + lh * 8;
  float4 xfa[16], xfb[16];
  #pragma unroll
  for (int K = 0; K < 16; ++K){
    xfa[K] = *(const float4*)(xp + K*16);
    xfb[K] = *(const float4*)(xp + K*16 + 4);
  }
  short8 xb[16];
  #pragma unroll
  for (int K = 0; K < 16; ++K){
    uint4 u;
    u.x = pk2(xfa[K].x, xfa[K].y); u.y = pk2(xfa[K].z, xfa[K].w);
    u.z = pk2(xfb[K].x, xfb[K].y); u.w = pk2(xfb[K].z, xfb[K].w);
    xb[K] = __builtin_bit_cast(short8, u);
  }

  // phase protocol: waitv (own staging for panel p drained) -> barrier (all waves') ->
  // read buf[p%3] + MFMA -> stage panel p+2 into buf[(p+2)%3] (overwrites panel p-1,
  // whose reads were consumed before the phase-p barrier). ONE barrier per phase.

  // ================= stage 1: X @ W1 -> GLU -> T1-frags =================
  short8 t1b[8];
  #pragma unroll
  for (int m = 0; m < 4; ++m){
    f32x16 accv = zero16(), accg = zero16();
    #pragma unroll
    for (int e = 0; e < 2; ++e){
      const int p = m*2 + e;
      waitv<4>(); barx();
      const unsigned char* bp = buf[p % 3];
      #pragma unroll
      for (int kb = 0; kb < 8; ++kb){
        short8 av = afrag(bp, cc,      kb, lh);
        short8 ag = afrag(bp, cc + 32, kb, lh);
        const int K = e*8 + kb;
        accv = __builtin_amdgcn_mfma_f32_32x32x16_bf16(av, xb[K], accv, 0, 0, 0);
        accg = __builtin_amdgcn_mfma_f32_32x32x16_bf16(ag, xb[K], accg, 0, 0, 0);
      }
      // stage panel p+2
      if (p <= 5) stage_panel<4>(ws + OFF_S1 + (p+2)*16384, buf[(p+2) % 3], w, l);
      else        stage_panel<4>(ws + OFF_S2 + (p-6)*16384, buf[(p+2) % 3], w, l);
    }
    // GLU epilogue -> packed words -> exchange -> frags kb 2m,2m+1
    unsigned W[8];
    #pragma unroll
    for (int q = 0; q < 4; ++q){
      float4 bv = *(const float4*)&blds[      m*32 + 8*q + 4*lh];
      float4 bg = *(const float4*)&blds[128 + m*32 + 8*q + 4*lh];
      float t0 = (accv[4*q+0] + bv.x) * frcp(1.f + fexp2n(accg[4*q+0] + bg.x));
      float t1 = (accv[4*q+1] + bv.y) * frcp(1.f + fexp2n(accg[4*q+1] + bg.y));
      float t2 = (accv[4*q+2] + bv.z) * frcp(1.f + fexp2n(accg[4*q+2] + bg.z));
      float t3 = (accv[4*q+3] + bv.w) * frcp(1.f + fexp2n(accg[4*q+3] + bg.w));
      W[2*q]   = pk2(t0, t1);
      W[2*q+1] = pk2(t2, t3);
    }
    frags_from_words(W, lh, &t1b[2*m], &t1b[2*m+1]);
  }

  // ================= stage 2: T1 @ W2 -> GLU -> T-frags =================
  short8 tb[8];
  #pragma unroll
  for (int m = 0; m < 4; ++m){
    const int p = 8 + m;
    f32x16 accv = zero16(), accg = zero16();
    if (p == 11) waitv<2>(); else waitv<4>();
    barx();
    const unsigned char* bp = buf[p % 3];
    #pragma unroll
    for (int kb = 0; kb < 8; ++kb){
      short8 av = afrag(bp, cc,      kb, lh);
      short8 ag = afrag(bp, cc + 32, kb, lh);
      accv = __builtin_amdgcn_mfma_f32_32x32x16_bf16(av, t1b[kb], accv, 0, 0, 0);
      accg = __builtin_amdgcn_mfma_f32_32x32x16_bf16(ag, t1b[kb], accg, 0, 0, 0);
    }
    if (p <= 9) stage_panel<4>(ws + OFF_S2 + (p-6)*16384, buf[(p+2) % 3], w, l);
    else        stage_panel<2>(ws + OFF_S3 + (p-10)*8192, buf[(p+2) % 3], w, l);
    unsigned W[8];
    #pragma unroll
    for (int q = 0; q < 4; ++q){
      float4 bv = *(const float4*)&blds[256 +       m*32 + 8*q + 4*lh];
      float4 bg = *(const float4*)&blds[256 + 128 + m*32 + 8*q + 4*lh];
      float t0 = (accv[4*q+0] + bv.x) * frcp(1.f + fexp2n(accg[4*q+0] + bg.x));
      float t1 = (accv[4*q+1] + bv.y) * frcp(1.f + fexp2n(accg[4*q+1] + bg.y));
      float t2 = (accv[4*q+2] + bv.z) * frcp(1.f + fexp2n(accg[4*q+2] + bg.z));
      float t3 = (accv[4*q+3] + bv.w) * frcp(1.f + fexp2n(accg[4*q+3] + bg.w));
      W[2*q]   = pk2(t0, t1);
      W[2*q+1] = pk2(t2, t3);
    }
    frags_from_words(W, lh, &tb[2*m], &tb[2*m+1]);
  }

  // ================= stage 3: T @ att_w4 -> z =================
  f32x16 zc[4];
  #pragma unroll
  for (int m = 0; m < 4; ++m){
    const int p = 12 + m;
    f32x16 acc = zero16();
    waitv<2>(); barx();
    const unsigned char* bp = buf[p % 3];
    #pragma unroll
    for (int kb = 0; kb < 8; ++kb){
      short8 a = afrag(bp, cc, kb, lh);
      acc = __builtin_amdgcn_mfma_f32_32x32x16_bf16(a, tb[kb], acc, 0, 0, 0);
    }
    if (p <= 13) stage_panel<2>(ws + OFF_S3 + (p-10)*8192, buf[(p+2) % 3], w, l);
    else         stage_panel<2>(ws + OFF_S4 + (p-14)*8192, buf[(p+2) % 3], w, l);
    #pragma unroll
    for (int q = 0; q < 4; ++q){
      float4 b3 = *(const float4*)&blds[512 + m*32 + 8*q + 4*lh];
      zc[m][4*q+0] = acc[4*q+0] + b3.x;
      zc[m][4*q+1] = acc[4*q+1] + b3.y;
      zc[m][4*q+2] = acc[4*q+2] + b3.z;
      zc[m][4*q+3] = acc[4*q+3] + b3.w;
    }
  }

  // ---- sparsemax per row (row = cc, halves on lanes l and l^32) ----
  float tau, cprev;
  {
    float s = 0.f;
    #pragma unroll
    for (int m = 0; m < 4; ++m)
      #pragma unroll
      for (int i = 0; i < 16; ++i) s += zc[m][i];
    s += sx32f(s);
    tau = (s - 1.f) * (1.f/128.f);
    cprev = 128.f;
  }
  for (int it = 0; it < 32; ++it){
    float s2 = 0.f, c2 = 0.f;
    #pragma unroll
    for (int m = 0; m < 4; ++m)
      #pragma unroll
      for (int i = 0; i < 16; ++i){
        float z = zc[m][i];
        if (z > tau){ s2 += z; c2 += 1.f; }
      }
    s2 += sx32f(s2); c2 += sx32f(c2);
    tau = (s2 - 1.f) / c2;
    int ch = (c2 != cprev);
    cprev = c2;
    if (!__any(ch)) break;
  }

  // ---- P-frags: exchange z to B-layout (f32), multiply with T, pack ----
  short8 pb[8];
  #pragma unroll
  for (int kb = 0; kb < 8; ++kb){
    const int chn = kb >> 1;
    const int ga = (kb & 1) * 2;
    float o[4], sn[4], rv[4];
    #pragma unroll
    for (int i = 0; i < 4; ++i){
      o[i]  = lh ? zc[chn][4*(ga+1) + i] : zc[chn][4*ga + i];
      sn[i] = lh ? zc[chn][4*ga + i]     : zc[chn][4*(ga+1) + i];
    }
    #pragma unroll
    for (int i = 0; i < 4; ++i) rv[i] = sx32f(sn[i]);
    float zB[8];
    #pragma unroll
    for (int i = 0; i < 4; ++i){
      zB[i]   = lh ? rv[i] : o[i];
      zB[4+i] = lh ? o[i]  : rv[i];
    }
    float P[8];
    #pragma unroll
    for (int j = 0; j < 8; ++j){
      float mk = zB[j] - tau;
      mk = mk > 0.f ? mk : 0.f;
      P[j] = bf2f(tb[kb][j]) * mk;
    }
    uint4 u;
    u.x = pk2(P[0], P[1]); u.y = pk2(P[2], P[3]);
    u.z = pk2(P[4], P[5]); u.w = pk2(P[6], P[7]);
    pb[kb] = __builtin_bit_cast(short8, u);
  }

  // ================= stage 4: P @ out_w + b -> acc4v[2] =================
  f32x16 acc4v[2];
  #pragma unroll
  for (int m = 0; m < 2; ++m){
    const int p = 16 + m;
    f32x16 acc = zero16();
    if (p == 17) waitv<0>(); else waitv<2>();
    barx();
    const unsigned char* bp = buf[p % 3];
    #pragma unroll
    for (int kb = 0; kb < 8; ++kb){
      short8 a = afrag(bp, cc, kb, lh);
      acc = __builtin_amdgcn_mfma_f32_32x32x16_bf16(a, pb[kb], acc, 0, 0, 0);
    }
    acc4v[m] = acc;
  }

  // ---- coalesced store: bounce through buf[0..1] (free after barrier-17) ----
  // per-wave 8KB region; row cc holds 256B (64 f32 cols), XOR-swizzled by (row&15)<<4
  {
    unsigned char* br = buf[0] + w * 8192;
    #pragma unroll
    for (int m = 0; m < 2; ++m){
      #pragma unroll
      for (int q = 0; q < 4; ++q){
        float4 b4 = *(const float4*)&blds[640 + m*32 + 8*q + 4*lh];
        float4 v;
        v.x = acc4v[m][4*q+0] + b4.x;
        v.y = acc4v[m][4*q+1] + b4.y;
        v.z = acc4v[m][4*q+2] + b4.z;
        v.w = acc4v[m][4*q+3] + b4.w;
        int wb = m*128 + q*32 + lh*16;
        *(float4*)(br + cc*256 + (wb ^ ((cc & 15) << 4))) = v;
      }
    }
    // lane-linear re-read -> 1KB-contiguous global stores (8 x dwordx4)
    char* gout = (char*)out + rowbase * 256;
    #pragma unroll
    for (int j = 0; j < 8; ++j){
      int r  = j*4 + (l >> 4);
      int wb = (l & 15) * 16;
      float4 v = *(const float4*)(br + r*256 + (wb ^ ((r & 15) << 4)));
      *(float4*)(gout + j*1024 + l*16) = v;
    }
  }
}

extern "C" void kernel_launch(void* const* d_in, const int* in_sizes, int n_in,
                              void* d_out, int out_size, void* d_ws, size_t ws_size,
                              hipStream_t stream)
{
  const float* feat = (const float*)d_in[0];
  const float* w1  = (const float*)d_in[1];
  const float* b1  = (const float*)d_in[2];
  const float* g1  = (const float*)d_in[3];
  const float* be1 = (const float*)d_in[4];
  const float* w2  = (const float*)d_in[5];
  const float* b2  = (const float*)d_in[6];
  const float* g2  = (const float*)d_in[7];
  const float* be2 = (const float*)d_in[8];
  const float* aw  = (const float*)d_in[9];
  const float* ab  = (const float*)d_in[10];
  const float* ag  = (const float*)d_in[11];
  const float* abe = (const float*)d_in[12];
  const float* ow  = (const float*)d_in[13];
  const float* ob  = (const float*)d_in[14];
  unsigned char* ws = (unsigned char*)d_ws;

  tabnet_prep<<<128, 256, 0, stream>>>(w1,b1,g1,be1, w2,b2,g2,be2, aw,ab,ag,abe, ow,ob, ws);
  tabnet_main<<<2048, 256, 0, stream>>>(feat, ws, (float*)d_out);
}